// Round 19
// baseline (43807.010 us; speedup 1.0000x reference)
//
#include <hip/hip_runtime.h>

// LayerNorm-LSTM, S=512 B=64 I=H=512 L=2, all I/O f32, all compute f32.
// (chaotic recurrence: any bf16 => absmax ~1.4 FAIL; deterministic-f32 order
//  noise => ~0.016 PASS. f32 VALU only, fixed reduction orders.)
//
// R19 = R18 (2 stream-ordered launches/tick; kernel boundaries are the only
// sync -- structurally minimal: h-handoff and LN-stats must each cross a
// sync point) with the gemm critical path symmetrized:
//  - x_T[2][512][64] ws buffer: cell_step(tau) transposes inputs[tau+1]
//    (init_k seeds tick 0). L0's x-half becomes a direct transposed-GEMM
//    like L1's -- A_lds staging and its 9 barriers deleted (LDS 152->83 KB).
//  - gemm_step: both layers run two identical 512-K GEMMT halves (h_T + x).
//  - cell_step: R6-proven row-local deterministic LN + cell, + x-transpose
//    appendix; writes h_T/y0_T transposed, out, h_n/c_n.
//  L1 lags L0 by one tick; single-buffer h_T/y0_T race-free by stream order.

typedef float f32x4 __attribute__((ext_vector_type(4)));

__device__ __forceinline__ float sigm(float x) { return 1.f / (1.f + __expf(-x)); }
__device__ __forceinline__ float tanh_f(float x) { return 2.f / (1.f + __expf(-2.f * x)) - 1.f; }

// one-time: h_T/c seeds (both layers) + x_T seed for tick 0
__global__ void init_k(const float* __restrict__ inputs,
                       const float* __restrict__ h0, const float* __restrict__ c0,
                       float* __restrict__ h_T, float* __restrict__ c_ws,
                       float* __restrict__ x_T) {
  const int nthr = gridDim.x * 256;
  for (int i = blockIdx.x * 256 + threadIdx.x; i < 2 * 64 * 512; i += nthr) {
    int l = i >> 15, rem = i & 32767, b = rem >> 9, hc = rem & 511;
    h_T[(l * 512 + hc) * 64 + b] = h0[i];
    c_ws[i] = c0[i];
  }
  for (int i = blockIdx.x * 256 + threadIdx.x; i < 512 * 64; i += nthr) {
    int k = i >> 6, b = i & 63;
    x_T[k * 64 + b] = inputs[b * 512 + k];   // tick 0 -> buffer 0
  }
}

__global__ __launch_bounds__(256)
void gemm_step(const float* __restrict__ x_T,
               const float* __restrict__ wx0, const float* __restrict__ wx1,
               const float* __restrict__ wh0, const float* __restrict__ wh1,
               const float* __restrict__ bias,
               const float* __restrict__ h_T, const float* __restrict__ y0_T,
               float* __restrict__ gates_ws, int tau)
{
  extern __shared__ float lds[];
  float* W_lds = lds;                  // [1024][16]  16384 f = 64 KB
  float* part  = lds + 16384;          // [4][64][17]  4352 f = 17 KB

  const int tid = threadIdx.x;
  const int wg = blockIdx.x;
  const int layer = wg >> 7;
  const int w = wg & 127;              // gate-col slice: hc [4w,4w+4) x 4 gates
  if (layer == 0 ? (tau >= 512) : (tau < 1)) return;

  const int wavet = tid >> 6, lane = tid & 63;
  const int rq = lane & 15;            // row quad -> rows 4rq..4rq+3
  const int gq = lane >> 4;            // gate (col quad)
  const int srow = tid >> 2, sg = tid & 3;

  const float* Wx = layer ? wx1 : wx0;
  const float* Wh = layer ? wh1 : wh0;

  // stage W slice: W_lds[k][g*4+j] = W[k][g*512+4w+j]
  for (int i = 0; i < 16; ++i) {
    int e = tid + i * 256;
    int k = e >> 2, g = e & 3;
    const float* src = (k < 512) ? (Wx + (size_t)k * 2048)
                                 : (Wh + (size_t)(k - 512) * 2048);
    *(f32x4*)&W_lds[k * 16 + g * 4] = *(const f32x4*)(src + g * 512 + 4 * w);
  }
  __syncthreads();

  f32x4 biasr = *(const f32x4*)(bias + layer * 2048 + sg * 512 + 4 * w);
  f32x4 acc[4];
#pragma unroll
  for (int r = 0; r < 4; ++r) acc[r] = (f32x4){0.f, 0.f, 0.f, 0.f};

  // transposed 512-K half-GEMM: T[512][64], W rows at wbase
  auto GEMMT = [&](const float* T, int wbase) {
    const int k0 = wavet * 128;
#pragma unroll 8
    for (int kk = 0; kk < 128; ++kk) {
      int k = k0 + kk;
      f32x4 av = *(const f32x4*)&T[k * 64 + 4 * rq];
      f32x4 wv = *(const f32x4*)&W_lds[(wbase + k) * 16 + gq * 4];
      acc[0] += av[0] * wv;
      acc[1] += av[1] * wv;
      acc[2] += av[2] * wv;
      acc[3] += av[3] * wv;
    }
  };

  GEMMT(h_T + layer * 32768, 512);                       // h-half
  GEMMT(layer ? y0_T : (x_T + (size_t)(tau & 1) * 32768), 0);  // x-half

  // ---- K-group partials -> LDS -> merged pre-LN gates (+bias) -> global
#pragma unroll
  for (int r = 0; r < 4; ++r)
#pragma unroll
    for (int cc = 0; cc < 4; ++cc)
      part[(wavet * 64 + 4 * rq + r) * 17 + gq * 4 + cc] = acc[r][cc];
  __syncthreads();
  {
    f32x4 pre;
#pragma unroll
    for (int cc = 0; cc < 4; ++cc) {
      float v = biasr[cc];
      v += part[(0 * 64 + srow) * 17 + sg * 4 + cc];
      v += part[(1 * 64 + srow) * 17 + sg * 4 + cc];
      v += part[(2 * 64 + srow) * 17 + sg * 4 + cc];
      v += part[(3 * 64 + srow) * 17 + sg * 4 + cc];
      pre[cc] = v;
    }
    *(f32x4*)&gates_ws[((size_t)layer * 64 + srow) * 2048 + sg * 512 + 4 * w] = pre;
  }
}

__global__ __launch_bounds__(256)
void cell_step(const float* __restrict__ gates_ws,
               const float* __restrict__ gamma_, const float* __restrict__ beta_,
               const float* __restrict__ inputs,
               float* __restrict__ c_ws, float* __restrict__ h_T,
               float* __restrict__ y0_T, float* __restrict__ x_T,
               float* __restrict__ out, int tau)
{
  __shared__ float sred[512];
  __shared__ float minv[8];
  __shared__ float gnorm[2048];

  const int tid = threadIdx.x;
  const int wgid = blockIdx.x;
  const int l = wgid >> 6, b = wgid & 63;
  if (l == 0 ? (tau >= 512) : (tau < 1)) return;
  const int t = l ? (tau - 1) : tau;

  const float* grow = gates_ws + ((size_t)l * 64 + b) * 2048;
  const int c0i = tid * 8;
  float acc[8];
#pragma unroll
  for (int j = 0; j < 8; ++j) acc[j] = grow[c0i + j];

  // x-transpose appendix: L0 WGs write x_T for tick tau+1 (double-buffered)
  if (l == 0 && tau < 511) {
    const float* xn = inputs + (size_t)(tau + 1) * 32768;
    float* xd = x_T + (size_t)((tau + 1) & 1) * 32768;
    int e0 = b * 512 + tid * 2;
    int k = e0 >> 6, b2 = e0 & 63;
    xd[k * 64 + b2] = xn[b2 * 512 + k];
    xd[k * 64 + b2 + 1] = xn[(b2 + 1) * 512 + k];
  }

  // R6-proven deterministic row-local LN stats
  {
    float s = 0.f, ss = 0.f;
#pragma unroll
    for (int j = 0; j < 8; ++j) { s += acc[j]; ss += acc[j] * acc[j]; }
    sred[tid * 2] = s; sred[tid * 2 + 1] = ss;
  }
  __syncthreads();
  if (tid < 4) {
    float S = 0.f, SS = 0.f;
    for (int u = 0; u < 64; ++u) {
      S += sred[(tid * 64 + u) * 2];
      SS += sred[(tid * 64 + u) * 2 + 1];
    }
    float mu = S * (1.f / 512.f);
    float var = SS * (1.f / 512.f) - mu * mu;
    minv[tid * 2] = mu;
    minv[tid * 2 + 1] = rsqrtf(fmaxf(var, 0.f) + 1e-5f);
  }
  __syncthreads();
  {
    int g = tid >> 6;
    float mu = minv[g * 2], inv = minv[g * 2 + 1];
#pragma unroll
    for (int j = 0; j < 8; ++j) {
      int c = c0i + j;
      gnorm[c] = (acc[j] - mu) * inv * gamma_[l * 2048 + c] + beta_[l * 2048 + c];
    }
  }
  __syncthreads();

#pragma unroll
  for (int v = 0; v < 2; ++v) {
    int hc = tid * 2 + v;
    float ig = sigm(gnorm[hc]);
    float fg = sigm(gnorm[512 + hc]);
    float og = sigm(gnorm[1024 + hc]);
    float ug = tanh_f(gnorm[1536 + hc]);
    float cs = fg * c_ws[l * 32768 + b * 512 + hc] + ig * ug;
    float hv = og * tanh_f(cs);
    c_ws[l * 32768 + b * 512 + hc] = cs;
    h_T[(l * 512 + hc) * 64 + b] = hv;       // transposed for next gemm_step
    if (l == 0) y0_T[hc * 64 + b] = hv;      // transposed handoff to L1
    else        out[(size_t)t * 32768 + b * 512 + hc] = hv;
    if (t == 511) {
      out[16777216 + l * 32768 + b * 512 + hc] = hv;   // h_n
      out[16842752 + l * 32768 + b * 512 + hc] = cs;   // c_n
    }
  }
}

extern "C" void kernel_launch(void* const* d_in, const int* in_sizes, int n_in,
                              void* d_out, int out_size, void* d_ws, size_t ws_size,
                              hipStream_t stream) {
  const float* inputs = (const float*)d_in[0];
  const float* h0 = (const float*)d_in[1];
  const float* c0 = (const float*)d_in[2];
  const float* wx0 = (const float*)d_in[3];
  const float* wx1 = (const float*)d_in[4];
  const float* wh0 = (const float*)d_in[5];
  const float* wh1 = (const float*)d_in[6];
  const float* bias = (const float*)d_in[7];
  const float* gamma_ = (const float*)d_in[8];
  const float* beta_ = (const float*)d_in[9];
  float* out = (float*)d_out;

  char* ws = (char*)d_ws;
  float* gates_ws = (float*)ws;                    // [2][64][2048]  1 MB
  float* h_T = (float*)(ws + 1048576);             // [2][512][64]   256 KB
  float* y0_T = (float*)(ws + 1310720);            // [512][64]      128 KB
  float* c_ws = (float*)(ws + 1441792);            // [2][64][512]   256 KB
  float* x_T = (float*)(ws + 1703936);             // [2][512][64]   256 KB

  const int smem_bytes = 20736 * 4;                // 82944 B
  hipFuncSetAttribute((const void*)gemm_step,
                      hipFuncAttributeMaxDynamicSharedMemorySize, smem_bytes);

  hipLaunchKernelGGL(init_k, dim3(256), dim3(256), 0, stream,
                     inputs, h0, c0, h_T, c_ws, x_T);

  for (int tau = 0; tau <= 512; ++tau) {
    hipLaunchKernelGGL(gemm_step, dim3(256), dim3(256), smem_bytes, stream,
                       x_T, wx0, wx1, wh0, wh1, bias, h_T, y0_T, gates_ws, tau);
    hipLaunchKernelGGL(cell_step, dim3(128), dim3(256), 0, stream,
                       gates_ws, gamma_, beta_, inputs, c_ws, h_T, y0_T, x_T, out, tau);
  }
}